// Round 6
// baseline (607.578 us; speedup 1.0000x reference)
//
#include <hip/hip_runtime.h>
#include <hip/hip_bf16.h>

// Problem constants (from setup_inputs)
#define N_EMB   6272
#define M_BANK  32768
#define D_DIM   128
#define KP      256      // packed rows: [hi(128) | lo(128)]
#define BATCH   8
#define P_PATCH 784      // 6272 / 8
#define GRID_WH 28
#define OUT_WH  224
#define KNN     9
#define KSIZE   33
#define KRAD    16

typedef unsigned long long ull;
typedef short bf16x8 __attribute__((ext_vector_type(8)));
typedef float f32x4  __attribute__((ext_vector_type(4)));

// ---------------- workspace layout (bytes) ----------------
#define WS_MINPACK 0          // u64[6272]        -> 50176
#define WS_X2      50176      // f32[6272]        -> 75264
#define WS_Y2      75264      // f32[32768]       -> 206336
#define WS_PSCORE  206336     // f32[6272]        -> 231424
#define WS_BSCORE  231424     // f32[8]
#define WS_BMAXP   231456     // i32[8]
#define WS_BNN     231488     // i32[8]
#define WS_CAND    231552     // u64[8*32*9]      -> 249984
#define WS_APK     249984     // u16[6272*256]    -> 3461248  (16B aligned)
#define WS_BPK     3461248    // u16[32768*256]   -> 20238464 (16B aligned)

__device__ __forceinline__ ull umin64(ull a, ull b) { return a < b ? a : b; }
__device__ __forceinline__ ull umax64(ull a, ull b) { return a > b ? a : b; }

__device__ __forceinline__ void gload_lds16(const void* g, void* l) {
    __builtin_amdgcn_global_load_lds(
        (const __attribute__((address_space(1))) void*)g,
        (__attribute__((address_space(3))) void*)l, 16, 0, 0);
}

// ---------------------------------------------------------------------------
// Kernel 0 (prep): per-row bf16 hi/lo split-pack [hi|lo] + sum-of-squares +
// minpack init. One wave per row.
// ---------------------------------------------------------------------------
__global__ __launch_bounds__(256) void prep_kernel(
    const float* __restrict__ emb, const float* __restrict__ bank,
    unsigned short* __restrict__ Apk, unsigned short* __restrict__ Bpk,
    float* __restrict__ x2, float* __restrict__ y2, ull* __restrict__ minpack)
{
    const int tid = threadIdx.x;
    int gi = blockIdx.x * 256 + tid;
    if (gi < N_EMB) minpack[gi] = ~0ull;

    const int w    = blockIdx.x * 4 + (tid >> 6);
    const int lane = tid & 63;
    const float* src;
    unsigned short* dst;
    float* sq;
    if (w < N_EMB) {
        src = emb + (size_t)w * D_DIM;
        dst = Apk + (size_t)w * KP;
        sq  = x2 + w;
    } else {
        int m = w - N_EMB;             // grid sized exactly -> m < M_BANK
        src = bank + (size_t)m * D_DIM;
        dst = Bpk + (size_t)m * KP;
        sq  = y2 + m;
    }
    float2 v = *(const float2*)&src[2 * lane];
    __hip_bfloat16 h0 = __float2bfloat16(v.x);
    __hip_bfloat16 h1 = __float2bfloat16(v.y);
    __hip_bfloat16 l0 = __float2bfloat16(v.x - __bfloat162float(h0));
    __hip_bfloat16 l1 = __float2bfloat16(v.y - __bfloat162float(h1));
    unsigned hb0 = *(unsigned short*)&h0, hb1 = *(unsigned short*)&h1;
    unsigned lb0 = *(unsigned short*)&l0, lb1 = *(unsigned short*)&l1;
    *(unsigned*)&dst[2 * lane]       = hb0 | (hb1 << 16);
    *(unsigned*)&dst[128 + 2 * lane] = lb0 | (lb1 << 16);

    float s = fmaf(v.x, v.x, v.y * v.y);
    #pragma unroll
    for (int off = 32; off > 0; off >>= 1) s += __shfl_down(s, off, 64);
    if (lane == 0) *sq = s;
}

// ---------------------------------------------------------------------------
// Kernel 1: MFMA distance + fused min/argmin.
// 128x128 tile, 16x16x32 bf16 MFMA, __syncthreads K-loop (compiler-managed
// waits; deterministic). BK=64 (6 iters, 32 MFMA/barrier). Virtual K=384 over
// [hi|lo] storage: sections hi*hi, hi*lo, lo*hi in that order (bit-identical
// to the previous [hi|hi|lo]x[hi|lo|hi] packing). XOR-swizzled k-slots: DMA
// fetches global slot (l&7)^(row&7) into LDS slot (l&7), so stride-128B frag
// reads spread across banks (2-way max, free).
// ---------------------------------------------------------------------------
__global__ __launch_bounds__(256) void mfma_min_kernel(
    const unsigned short* __restrict__ Apk, const unsigned short* __restrict__ Bpk,
    const float* __restrict__ x2, const float* __restrict__ y2,
    ull* __restrict__ minpack)
{
    __shared__ __align__(16) unsigned short Asm_[128 * 64];  // 16 KB
    __shared__ __align__(16) unsigned short Bsm_[128 * 64];  // 16 KB

    const int tid  = threadIdx.x;
    const int lane = tid & 63;
    const int wave = tid >> 6;
    const int wr = wave >> 1, wc = wave & 1;
    const int n0 = blockIdx.y * 128;
    const int m0 = blockIdx.x * 128;

    const int qa = lane >> 4;    // k-quad
    const int ra = lane & 15;    // row-in-frag / col-in-C
    const int r7 = ra & 7;

    // staging: wave issues gloads q = wave*4+j; lane l covers row q*8+(l>>3),
    // LDS k-slot (l&7) holding global k-slot (l&7)^((l>>3)&7).
    const int swz = ((lane & 7) ^ ((lane >> 3) & 7)) * 8;
    const unsigned short* gA[4];
    const unsigned short* gB[4];
    #pragma unroll
    for (int j = 0; j < 4; ++j) {
        const int q  = wave * 4 + j;
        const int rw = q * 8 + (lane >> 3);
        gA[j] = Apk + (size_t)(n0 + rw) * KP + swz;
        gB[j] = Bpk + (size_t)(m0 + rw) * KP + swz;
    }

    const int slot0 = ( qa      ^ r7) * 8;   // sub-chunk kc=0
    const int slot1 = ((4 + qa) ^ r7) * 8;   // sub-chunk kc=1
    int aRB[4], bRB[4];
    #pragma unroll
    for (int i = 0; i < 4; ++i) {
        aRB[i] = (wr * 64 + i * 16 + ra) * 64;
        bRB[i] = (wc * 64 + i * 16 + ra) * 64;
    }

    f32x4 acc[4][4];
    #pragma unroll
    for (int i = 0; i < 4; ++i)
        #pragma unroll
        for (int j = 0; j < 4; ++j)
            acc[i][j] = (f32x4){0.f, 0.f, 0.f, 0.f};

    for (int it = 0; it < 6; ++it) {
        const int sec = it >> 1;                       // 0: h*h, 1: h*l, 2: l*h
        const int ka  = (sec == 2 ? 128 : 0) + (it & 1) * 64;
        const int kb  = (sec == 1 ? 128 : 0) + (it & 1) * 64;
        __syncthreads();
        #pragma unroll
        for (int j = 0; j < 4; ++j) {
            gload_lds16(gA[j] + ka, &Asm_[(wave * 4 + j) * 512]);
            gload_lds16(gB[j] + kb, &Bsm_[(wave * 4 + j) * 512]);
        }
        __syncthreads();
        #pragma unroll
        for (int kc = 0; kc < 2; ++kc) {
            const int sl = kc ? slot1 : slot0;
            bf16x8 af[4], bfr[4];
            #pragma unroll
            for (int i = 0; i < 4; ++i)
                af[i] = *(const bf16x8*)&Asm_[aRB[i] + sl];
            #pragma unroll
            for (int j = 0; j < 4; ++j)
                bfr[j] = *(const bf16x8*)&Bsm_[bRB[j] + sl];
            #pragma unroll
            for (int i = 0; i < 4; ++i)
                #pragma unroll
                for (int j = 0; j < 4; ++j)
                    acc[i][j] = __builtin_amdgcn_mfma_f32_16x16x32_bf16(af[i], bfr[j], acc[i][j], 0, 0, 0);
        }
    }

    // ---- epilogue: d2 = x2 + y2 - 2*dot, clamp, pack, reduce ----
    float y2v[4];
    #pragma unroll
    for (int j = 0; j < 4; ++j) y2v[j] = y2[m0 + wc * 64 + j * 16 + ra];

    __syncthreads();                 // all frag reads done; reuse Asm_ as red
    ull* red = (ull*)Asm_;           // [128 rows][2 col-halves]
    #pragma unroll
    for (int i = 0; i < 4; ++i) {
        #pragma unroll
        for (int r = 0; r < 4; ++r) {
            const int rowl = wr * 64 + i * 16 + qa * 4 + r;
            const float xv = x2[n0 + rowl];
            ull mn = ~0ull;
            #pragma unroll
            for (int j = 0; j < 4; ++j) {
                const int m = m0 + wc * 64 + j * 16 + ra;
                float d2 = fmaf(-2.0f, acc[i][j][r], xv + y2v[j]);
                d2 = fmaxf(d2, 0.0f);
                ull p = ((ull)__float_as_uint(d2) << 32) | (unsigned)m;
                mn = umin64(mn, p);
            }
            #pragma unroll
            for (int s = 1; s < 16; s <<= 1)
                mn = umin64(mn, (ull)__shfl_xor(mn, s, 64));
            if (ra == 0) red[rowl * 2 + wc] = mn;
        }
    }
    __syncthreads();
    if (tid < 128)
        atomicMin(&minpack[n0 + tid], umin64(red[tid * 2], red[tid * 2 + 1]));
}

// ---------------------------------------------------------------------------
// Kernel 2: per-batch argmax of patch scores (fused unpack); writes pscore.
// ---------------------------------------------------------------------------
__global__ __launch_bounds__(256) void batch_argmax_kernel(
    const ull* __restrict__ minpack, float* __restrict__ pscore,
    float* __restrict__ bscore, int* __restrict__ bmaxp, int* __restrict__ bnn)
{
    __shared__ ull red[256];
    int b = blockIdx.x, tid = threadIdx.x;
    ull local = 0;
    for (int p = tid; p < P_PATCH; p += 256) {
        ull mp = minpack[b * P_PATCH + p];
        unsigned d2b = (unsigned)(mp >> 32);
        pscore[b * P_PATCH + p] = sqrtf(__uint_as_float(d2b));
        ull pk = ((ull)d2b << 32) | (unsigned)(p ^ 0xFFFFFFFFu);
        local = umax64(local, pk);
    }
    red[tid] = local;
    __syncthreads();
    for (int s = 128; s > 0; s >>= 1) {
        if (tid < s) red[tid] = umax64(red[tid], red[tid + s]);
        __syncthreads();
    }
    if (tid == 0) {
        ull r = red[0];
        int p = (int)(((unsigned)(r & 0xFFFFFFFFu)) ^ 0xFFFFFFFFu);
        bscore[b] = sqrtf(__uint_as_float((unsigned)(r >> 32)));
        bmaxp[b]  = p;
        bnn[b]    = (int)(minpack[b * P_PATCH + p] & 0xFFFFFFFFu);
    }
}

// ---------------------------------------------------------------------------
// Kernel 3 (fused dnn + per-chunk top-9): grid (32 chunks, 8 batches).
// Block computes d_nn for its 1024 bank rows (identical fma/shfl order to the
// old dnn_kernel -> bit-identical values), then 9 rounds of LDS tree-min.
// ---------------------------------------------------------------------------
__global__ __launch_bounds__(256) void dnntopk_kernel(
    const float* __restrict__ bank, const float* __restrict__ y2,
    const int* __restrict__ bnn, ull* __restrict__ cand)
{
    __shared__ float nn[D_DIM];
    __shared__ float nny2s;
    __shared__ ull vals[1024];
    __shared__ ull red[256];
    const int tid = threadIdx.x;
    const int ch = blockIdx.x, b = blockIdx.y;
    const int base = ch * 1024;

    const int nnidx = bnn[b];
    if (tid < D_DIM) nn[tid] = bank[(size_t)nnidx * D_DIM + tid];
    if (tid == 0) nny2s = y2[nnidx];
    __syncthreads();

    const int w = tid >> 6, lane = tid & 63;
    const float na = nn[2 * lane], nb = nn[2 * lane + 1];
    for (int rep = 0; rep < 256; ++rep) {
        const int r = rep * 4 + w;
        const int m = base + r;
        float2 v = *(const float2*)&bank[(size_t)m * D_DIM + 2 * lane];
        float s = fmaf(v.x, na, v.y * nb);
        #pragma unroll
        for (int off = 32; off > 0; off >>= 1) s += __shfl_down(s, off, 64);
        if (lane == 0) {
            float d2 = nny2s + y2[m] - 2.0f * s;
            float d = sqrtf(fmaxf(d2, 0.0f));
            vals[r] = ((ull)__float_as_uint(d) << 32) | (unsigned)m;
        }
    }
    __syncthreads();

    for (int k = 0; k < KNN; ++k) {
        ull local = vals[tid];
        #pragma unroll
        for (int j = 1; j < 4; ++j) local = umin64(local, vals[tid + j * 256]);
        red[tid] = local;
        __syncthreads();
        for (int s = 128; s > 0; s >>= 1) {
            if (tid < s) red[tid] = umin64(red[tid], red[tid + s]);
            __syncthreads();
        }
        ull win = red[0];
        if (tid == 0) cand[(b * 32 + ch) * KNN + k] = win;
        #pragma unroll
        for (int j = 0; j < 4; ++j)
            if (vals[tid + j * 256] == win) vals[tid + j * 256] = ~0ull;
        __syncthreads();
    }
}

// ---------------------------------------------------------------------------
// Kernel 4 (role-branched): blocks 0..7 = final top-9 + rescore -> out[0..7];
// blocks 8..63 = fused resize+blur bands -> out[8..]. Shared LDS overlay.
// ---------------------------------------------------------------------------
__device__ __forceinline__ int refl224(int i) {
    if (i < 0) i = -i;
    if (i >= OUT_WH) i = 2 * (OUT_WH - 1) - i;
    return i;
}

__global__ __launch_bounds__(256) void final_blur_kernel(
    const ull* __restrict__ cand,
    const float* __restrict__ emb, const float* __restrict__ bank,
    const float* __restrict__ x2, const float* __restrict__ y2,
    const float* __restrict__ bscore, const int* __restrict__ bmaxp,
    const float* __restrict__ pscore, float* __restrict__ out)
{
    __shared__ __align__(16) char smem_raw[57344];
    const int tid = threadIdx.x;

    if (blockIdx.x < 8) {
        // ---------------- role A: final top-9 + rescore ----------------
        ull* vals    = (ull*)smem_raw;          // 512
        ull* red     = vals + 512;              // 256
        int* chosen  = (int*)(red + 256);       // KNN (pad 16)
        float* dists = (float*)(chosen + 16);   // KNN
        const int b = blockIdx.x;

        vals[tid]       = (tid < 32 * KNN) ? cand[b * 32 * KNN + tid] : ~0ull;
        vals[tid + 256] = (tid + 256 < 32 * KNN) ? cand[b * 32 * KNN + tid + 256] : ~0ull;
        __syncthreads();

        for (int k = 0; k < KNN; ++k) {
            red[tid] = umin64(vals[tid], vals[tid + 256]);
            __syncthreads();
            for (int s = 128; s > 0; s >>= 1) {
                if (tid < s) red[tid] = umin64(red[tid], red[tid + s]);
                __syncthreads();
            }
            ull win = red[0];
            if (tid == 0) chosen[k] = (int)(win & 0xFFFFFFFFu);
            if (vals[tid] == win) vals[tid] = ~0ull;
            if (vals[tid + 256] == win) vals[tid + 256] = ~0ull;
            __syncthreads();
        }

        const int e = b * P_PATCH + bmaxp[b];
        if (tid < KNN) {
            const float* mf = emb + (size_t)e * D_DIM;
            const float* ms = bank + (size_t)chosen[tid] * D_DIM;
            float dot = 0.0f;
            for (int d = 0; d < D_DIM; ++d) dot = fmaf(mf[d], ms[d], dot);
            float d2 = x2[e] - 2.0f * dot + y2[chosen[tid]];
            dists[tid] = sqrtf(fmaxf(d2, 0.0f));
        }
        __syncthreads();
        if (tid == 0) {
            float mx = dists[0];
            for (int k = 1; k < KNN; ++k) mx = fmaxf(mx, dists[k]);
            float s = 0.0f;
            for (int k = 0; k < KNN; ++k) s += expf(dists[k] - mx);
            float w = 1.0f - expf(dists[0] - mx) / s;
            out[b] = w * bscore[b];
        }
    } else {
        // ---------------- role B: fused resize + separable blur ----------------
        float* q    = (float*)smem_raw;         // 28*224
        float* hq   = q + GRID_WH * OUT_WH;     // 28*224
        float* ps   = hq + GRID_WH * OUT_WH;    // 784
        float* wrow = ps + P_PATCH;             // 32*28
        float* g    = wrow + 32 * GRID_WH;      // 33

        const int idx  = blockIdx.x - 8;
        const int band = idx % 7;               // 0..6
        const int b    = idx / 7;               // 0..7

        if (tid < KSIZE) {
            float x = (tid - KRAD) * 0.25f;     // / SIGMA=4
            g[tid] = __expf(-0.5f * x * x);
        }
        for (int i = tid; i < P_PATCH; i += 256) ps[i] = pscore[b * P_PATCH + i];
        __syncthreads();
        if (tid == 0) {
            float s = 0.0f;
            for (int i = 0; i < KSIZE; ++i) s += g[i];
            float inv = 1.0f / s;
            for (int i = 0; i < KSIZE; ++i) g[i] *= inv;
        }
        __syncthreads();

        for (int i = tid; i < GRID_WH * OUT_WH; i += 256) {
            int gy = i / OUT_WH, x = i - gy * OUT_WH;
            float cx = (2 * x - 7) * 0.0625f;
            int ix = (int)floorf(cx); float fx = cx - ix;
            int x0 = min(max(ix, 0), GRID_WH - 1), x1 = min(max(ix + 1, 0), GRID_WH - 1);
            q[i] = ps[gy * GRID_WH + x0] * (1.0f - fx) + ps[gy * GRID_WH + x1] * fx;
        }

        if (tid < 32) {
            int y = band * 32 + tid;
            for (int gy = 0; gy < GRID_WH; ++gy) wrow[tid * GRID_WH + gy] = 0.0f;
            for (int t = 0; t < KSIZE; ++t) {
                int yy = refl224(y - KRAD + t);
                float cy = (2 * yy - 7) * 0.0625f;
                int iy = (int)floorf(cy); float fy = cy - iy;
                int y0 = min(max(iy, 0), GRID_WH - 1), y1 = min(max(iy + 1, 0), GRID_WH - 1);
                wrow[tid * GRID_WH + y0] += g[t] * (1.0f - fy);
                wrow[tid * GRID_WH + y1] += g[t] * fy;
            }
        }
        __syncthreads();

        for (int i = tid; i < GRID_WH * OUT_WH; i += 256) {
            int gy = i / OUT_WH, x = i - gy * OUT_WH;
            float s = 0.0f;
            #pragma unroll
            for (int t = 0; t < KSIZE; ++t)
                s = fmaf(g[t], q[gy * OUT_WH + refl224(x - KRAD + t)], s);
            hq[i] = s;
        }
        __syncthreads();

        const int yl = tid >> 3;                 // 0..31
        const int xbase = (tid & 7) * 28;        // 8 groups x 28 px
        const int y = band * 32 + yl;
        float* orow = out + BATCH + ((size_t)b * OUT_WH + y) * OUT_WH;
        for (int i = 0; i < 28; ++i) {
            int x = xbase + i;
            float s = 0.0f;
            #pragma unroll
            for (int gy = 0; gy < GRID_WH; ++gy)
                s = fmaf(wrow[yl * GRID_WH + gy], hq[gy * OUT_WH + x], s);
            orow[x] = s;
        }
    }
}

// ---------------------------------------------------------------------------
extern "C" void kernel_launch(void* const* d_in, const int* in_sizes, int n_in,
                              void* d_out, int out_size, void* d_ws, size_t ws_size,
                              hipStream_t stream) {
    const float* emb  = (const float*)d_in[0];
    const float* bank = (const float*)d_in[1];
    float* out = (float*)d_out;

    char* ws = (char*)d_ws;
    ull*   minpack = (ull*)(ws + WS_MINPACK);
    float* x2      = (float*)(ws + WS_X2);
    float* y2      = (float*)(ws + WS_Y2);
    float* pscore  = (float*)(ws + WS_PSCORE);
    float* bscore  = (float*)(ws + WS_BSCORE);
    int*   bmaxp   = (int*)(ws + WS_BMAXP);
    int*   bnn     = (int*)(ws + WS_BNN);
    ull*   cand    = (ull*)(ws + WS_CAND);
    unsigned short* Apk = (unsigned short*)(ws + WS_APK);
    unsigned short* Bpk = (unsigned short*)(ws + WS_BPK);

    // 0: split-pack + sumsq + minpack init
    prep_kernel<<<(N_EMB + M_BANK) / 4, 256, 0, stream>>>(emb, bank, Apk, Bpk, x2, y2, minpack);
    // 1: MFMA distance + fused min/argmin
    {
        dim3 grid(M_BANK / 128, N_EMB / 128);   // 256 x 49
        mfma_min_kernel<<<grid, 256, 0, stream>>>(Apk, Bpk, x2, y2, minpack);
    }
    // 2: per-batch argmax (+ pscore unpack)
    batch_argmax_kernel<<<BATCH, 256, 0, stream>>>(minpack, pscore, bscore, bmaxp, bnn);
    // 3: fused d_nn + per-chunk top-9
    {
        dim3 grid(32, BATCH);
        dnntopk_kernel<<<grid, 256, 0, stream>>>(bank, y2, bnn, cand);
    }
    // 4: role-branched final top-9+rescore (blocks 0..7) and blur (8..63)
    final_blur_kernel<<<64, 256, 0, stream>>>(cand, emb, bank, x2, y2, bscore, bmaxp, pscore, out);
}